// Round 11
// baseline (515.043 us; speedup 1.0000x reference)
//
#include <hip/hip_runtime.h>
#include <hip/hip_bf16.h>
#include <cstdint>

// ---------------------------------------------------------------------------
// WorldModel RSSM: B=1024 T=50 E=1024 A=6 S=200 H=200 L=30
// fp32 in/out; internal GEMMs bf16 MFMA w/ fp32 accum.
//
//   k1: GI[bt,0:600]=concat(a,e)@W_ih+b_ih ; GI[bt,600:800]=e@Wq1[200:]+bq1
//       FULL-N blocks (128x800): each embed row staged exactly once ->
//       staged traffic 1.69GB -> 0.85GB. Counted-vmcnt 2-deep pipeline,
//       A fp32 XOR-bank-swizzled (rule-21 both-sides), 132KB LDS dbuf.
//   k2: GRU scan, 64 blocks x 8 waves, W_hh resident in regs (round 7).
//   k3: heads (fc_prior/fc_posterior + softplus + rsample) fully parallel.
// ---------------------------------------------------------------------------

typedef __attribute__((ext_vector_type(8))) short   short8;
typedef __attribute__((ext_vector_type(8))) __bf16  bf16x8;
typedef __attribute__((ext_vector_type(4))) float   f32x4;

__device__ __forceinline__ float bf2f(unsigned short u) {
    unsigned int v = ((unsigned int)u) << 16;
    return __builtin_bit_cast(float, v);
}
__device__ __forceinline__ unsigned short f2bf(float f) {
    unsigned int v = __builtin_bit_cast(unsigned int, f);
    v = v + 0x7FFFu + ((v >> 16) & 1u);   // RNE
    return (unsigned short)(v >> 16);
}
__device__ __forceinline__ float softplusf(float x) {
    return (x > 20.f) ? x : log1pf(__expf(x));
}
__device__ __forceinline__ void gload_lds16(const void* g, void* l) {
    __builtin_amdgcn_global_load_lds(
        (const __attribute__((address_space(1))) void*)g,
        (__attribute__((address_space(3))) void*)l, 16, 0, 0);
}

// ---------------- workspace layout (bytes) ----------------
#define OFF_BPACK 81920000
#define OFF_WHH   83558400
#define OFF_WPQ1  83837952
#define OFF_WPQ2  84024320

// fragment mapping (mfma_f32_16x16x32_bf16):
//   A[l&15][(l>>4)*8+j], B[(l>>4)*8+j][l&15], D[(l>>4)*4+r][l&15]
// packed B storage: elem = ((kk*NT + nt)*64 + l)*8 + j

__global__ __launch_bounds__(256) void pack_kernel(
    const float* __restrict__ W_ih, const float* __restrict__ W_hh,
    const float* __restrict__ Wp1,  const float* __restrict__ Wq1,
    const float* __restrict__ Wp2,  const float* __restrict__ Wq2,
    unsigned short* __restrict__ Bpack, unsigned short* __restrict__ Whh_p,
    unsigned short* __restrict__ Wpq1,  unsigned short* __restrict__ Wpq2)
{
    int e = blockIdx.x * 256 + threadIdx.x;
    if (e < 819200) {                       // k1: K=1024(embed), N=800
        const int j = e & 7, l = (e >> 3) & 63;
        const int nt = (e >> 9) % 50, kk = e / (512 * 50);
        const int k = kk * 32 + (l >> 4) * 8 + j;
        const int c = nt * 16 + (l & 15);
        Bpack[e] = f2bf((c < 600) ? W_ih[(6 + k) * 600 + c]
                                  : Wq1[(200 + k) * 200 + (c - 600)]);
        return;
    }
    e -= 819200;
    if (e < 139776) {                       // W_hh: K pad 224, N = 3 gates x 13 tiles
        const int j = e & 7, l = (e >> 3) & 63;
        const int nt = (e >> 9) % 39, kk = e / (512 * 39);
        const int k = kk * 32 + (l >> 4) * 8 + j;
        const int g = nt / 13, st = nt % 13;
        const int c = st * 16 + (l & 15);
        Whh_p[e] = (k < 200 && c < 200) ? f2bf(W_hh[k * 600 + g * 200 + c]) : (unsigned short)0;
        return;
    }
    e -= 139776;
    if (e < 93184) {                        // heads1: [Wp1 | Wq1[:200]] K pad 224
        const int j = e & 7, l = (e >> 3) & 63;
        const int nt = (e >> 9) % 26, kk = e / (512 * 26);
        const int k = kk * 32 + (l >> 4) * 8 + j;
        unsigned short v = 0;
        if (nt < 13) { const int c = nt * 16 + (l & 15);        if (k < 200 && c < 200) v = f2bf(Wp1[k * 200 + c]); }
        else         { const int c = (nt - 13) * 16 + (l & 15); if (k < 200 && c < 200) v = f2bf(Wq1[k * 200 + c]); }
        Wpq1[e] = v;
        return;
    }
    e -= 93184;
    if (e < 28672) {                        // heads2: [Wp2 | Wq2] N pad 64 each
        const int j = e & 7, l = (e >> 3) & 63;
        const int nt = (e >> 9) % 8, kk = e / (512 * 8);
        const int k = kk * 32 + (l >> 4) * 8 + j;
        unsigned short v = 0;
        if (nt < 4) { const int c = nt * 16 + (l & 15);       if (k < 200 && c < 60) v = f2bf(Wp2[k * 60 + c]); }
        else        { const int c = (nt - 4) * 16 + (l & 15); if (k < 200 && c < 60) v = f2bf(Wq2[k * 60 + c]); }
        Wpq2[e] = v;
    }
}

// ---------------- kernel 1: GI/QE GEMM  M=51200 N=800 K=1024 ----------------
// grid 400 = 400 M-chunks(128 rows) x FULL N (800 = 50 tiles).
// 512 thr = 8 waves = (mh 0..3) x (nh 0..1); wave = 2 M-subtiles x 25 N-tiles
// (acc[2][25] = 200 VGPR). Buffer (bytes): [0,51200) B 50 tiles;
// [51200,67584) A 128 rows x 128B fp32 XOR-swizzled. 66 stage chunks/K-step.
// Pipeline: issue(kk+1) -> vmcnt(Lw) -> bar -> compute -> lgkm(0) -> bar.
#define K1_BYTES 67584
__global__ __launch_bounds__(512, 2) void k1_gi(
    const float* __restrict__ embed,   // [51200][1024]
    const float* __restrict__ action,  // [51200][6]
    const float* __restrict__ W_ih,    // rows 0..5 = action part
    const float* __restrict__ b_ih,
    const float* __restrict__ bq1,
    const unsigned short* __restrict__ Bpack,
    unsigned short* __restrict__ GI)   // [51200][800] bf16
{
    __shared__ char bufS[2][K1_BYTES];

    const int tid = threadIdx.x;
    const int w = tid >> 6, l = tid & 63;
    const int lo = l & 15, hi = l >> 4;
    const int mh = w >> 1;                 // 0..3 -> M-subtile pair
    const int nh = w & 1;                  // 0..1 -> N-half (25 tiles)
    const int rb = blockIdx.x * 128;

    // ---- stage-chunk setup: 66 chunks (50 B + 16 A), wave w does j = w + 8i
    const char* sp[9]; int st[9]; int dof[9];
    const int nch = (w < 2) ? 9 : 8;
#pragma unroll
    for (int i = 0; i < 9; ++i) {
        int j = w + 8 * i; if (j >= 66) j = 65;
        if (j < 50) {                      // B tile j: 1KB linear from Bpack
            sp[i]  = (const char*)Bpack + (size_t)j * 1024 + l * 16;
            st[i]  = 50 * 1024;            // bytes per kk
            dof[i] = j * 1024;
        } else {                           // A chunk: 8 rows x 128B, source
            const int a = j - 50;          // quad-permuted -> LDS swizzled
            sp[i]  = (const char*)embed
                   + (size_t)(rb + a * 8 + (l >> 3)) * 4096
                   + (((l & 7) ^ (l >> 3)) << 4);
            st[i]  = 128;                  // bytes per kk
            dof[i] = 51200 + a * 1024;
        }
    }

    f32x4 acc[2][25];
#pragma unroll
    for (int m = 0; m < 2; ++m)
#pragma unroll
        for (int i = 0; i < 25; ++i) acc[m][i] = f32x4{0.f, 0.f, 0.f, 0.f};

    // ---- prologue: issue stage kk=0 -> buf0 (no wait here)
#pragma unroll
    for (int i = 0; i < 9; ++i) if (i < nch) {
        gload_lds16(sp[i], &bufS[0][dof[i]]);
        sp[i] += st[i];
    }

    // ---- main loop
    int cur = 0;
    for (int kk = 0; kk < 32; ++kk) {
        const int nxt = cur ^ 1;
        if (kk < 31) {
#pragma unroll
            for (int i = 0; i < 9; ++i) if (i < nch) {
                gload_lds16(sp[i], &bufS[nxt][dof[i]]);
                sp[i] += st[i];
            }
            if (w < 2) asm volatile("s_waitcnt vmcnt(9)" ::: "memory");
            else       asm volatile("s_waitcnt vmcnt(8)" ::: "memory");
        } else {
            asm volatile("s_waitcnt vmcnt(0)" ::: "memory");
        }
        __builtin_amdgcn_s_barrier();          // buf cur fully staged
        __builtin_amdgcn_sched_barrier(0);

        // A fragments: swizzled read (bank-uniform) + fp32->bf16 convert
        const float* Af = (const float*)&bufS[cur][51200];
        bf16x8 af[2];
#pragma unroll
        for (int m = 0; m < 2; ++m) {
            const int row = (mh * 2 + m) * 16 + lo;
            const int sw  = (row & 7) << 2;            // float-index XOR
            const float* base = Af + row * 32;
            f32x4 v0 = *(const f32x4*)(base + ((hi * 8) ^ sw));
            f32x4 v1 = *(const f32x4*)(base + ((hi * 8 + 4) ^ sw));
            bf16x8 t;
#pragma unroll
            for (int q = 0; q < 4; ++q) { t[q] = (__bf16)v0[q]; t[4 + q] = (__bf16)v1[q]; }
            af[m] = t;
        }
#pragma unroll
        for (int i = 0; i < 25; ++i) {
            bf16x8 b = __builtin_bit_cast(bf16x8,
                *(const short8*)&bufS[cur][(nh * 25 + i) * 1024 + l * 16]);
            acc[0][i] = __builtin_amdgcn_mfma_f32_16x16x32_bf16(af[0], b, acc[0][i], 0, 0, 0);
            acc[1][i] = __builtin_amdgcn_mfma_f32_16x16x32_bf16(af[1], b, acc[1][i], 0, 0, 0);
        }

        asm volatile("s_waitcnt lgkmcnt(0)" ::: "memory");   // all LDS reads done
        __builtin_amdgcn_s_barrier();          // buf cur may be overwritten next
        __builtin_amdgcn_sched_barrier(0);
        cur = nxt;
    }

    // ---- epilogue: bias + action(K=6) contribution, store bf16
#pragma unroll
    for (int m = 0; m < 2; ++m) {
        const int rbase = rb + (mh * 2 + m) * 16 + hi * 4;
        float av[4][6];
#pragma unroll
        for (int r = 0; r < 4; ++r)
#pragma unroll
            for (int k = 0; k < 6; ++k) av[r][k] = action[(size_t)(rbase + r) * 6 + k];
#pragma unroll
        for (int i = 0; i < 25; ++i) {
            const int col = (nh * 25 + i) * 16 + lo;
            const float bias = (col < 600) ? b_ih[col] : bq1[col - 600];
            float wa[6];
            if (col < 600) {
#pragma unroll
                for (int k = 0; k < 6; ++k) wa[k] = W_ih[k * 600 + col];
            }
#pragma unroll
            for (int r = 0; r < 4; ++r) {
                float v = acc[m][i][r] + bias;
                if (col < 600) {
#pragma unroll
                    for (int k = 0; k < 6; ++k) v += av[r][k] * wa[k];
                }
                GI[(size_t)(rbase + r) * 800 + col] = f2bf(v);
            }
        }
    }
}

// ---------------- kernel 2: GRU scan, 8 waves, resident weights ----------------
#define HSTRB 232   // hS row stride in bf16 elems (K pad >=224)
#define GSTR  227   // gAll row stride in floats (odd-ish vs 32 banks)

__global__ __launch_bounds__(512, 2) void k2_scan(
    unsigned short* __restrict__ GI,           // [51200][800] bf16 (deter -> cols 0..199)
    const unsigned short* __restrict__ Whh_p,
    const float* __restrict__ b_hh,
    float* __restrict__ out)                   // [51200][350] fp32 (cols 0..199 here)
{
    __shared__ unsigned short hS[16 * HSTRB];                 // 7424 B, bf16 h
    __shared__ float gAll[3 * 16 * GSTR];                     // 43584 B
    __shared__ __align__(16) unsigned short GIbuf[2][12288];  // 49152 B

    const int tid = threadIdx.x;
    const int w = tid >> 6, l = tid & 63;
    const int lo = l & 15, hi = l >> 4;
    const int r0 = blockIdx.x * 16;

    for (int i = tid; i < 16 * HSTRB; i += 512) hS[i] = 0;

    const int t0 = w * 5;
    const int ntl = (w == 7) ? 4 : 5;
    bf16x8 wf[5][7];
#pragma unroll
    for (int i = 0; i < 5; ++i)
#pragma unroll
        for (int kk = 0; kk < 7; ++kk)
            if (i < ntl)
                wf[i][kk] = __builtin_bit_cast(bf16x8,
                    *(const short8*)&Whh_p[((kk * 39 + (t0 + i)) * 64 + l) * 8]);

    int gOff[5];
#pragma unroll
    for (int i = 0; i < 5; ++i) {
        int nt = t0 + i; if (nt > 38) nt = 38;
        const int g = nt / 13, st = nt - g * 13;
        gOff[i] = (g * 16 + hi * 4) * GSTR + st * 16 + lo;
    }

    const char* srcB[3];
#pragma unroll
    for (int i = 0; i < 3; ++i) {
        int j = (i * 8 + w) * 64 + l;
        int rj = j / 75; int cj = j - rj * 75;
        if (rj > 15) { rj = 15; cj = 74; }
        srcB[i] = (const char*)GI + (size_t)(r0 + rj) * 50 * 1600 + (size_t)cj * 16;
    }

    const int c = tid & 255;
    const int rh = tid >> 8;
    const bool act = (c < 200);
    float bh0 = 0.f, bh1 = 0.f, bh2 = 0.f;
    if (act) { bh0 = b_hh[c]; bh1 = b_hh[200 + c]; bh2 = b_hh[400 + c]; }
    float h_reg[8] = {0.f, 0.f, 0.f, 0.f, 0.f, 0.f, 0.f, 0.f};

    {
#pragma unroll
        for (int i = 0; i < 3; ++i)
            gload_lds16(srcB[i], &GIbuf[0][(i * 8 + w) * 512]);
    }
    asm volatile("s_waitcnt lgkmcnt(0)" ::: "memory");
    __builtin_amdgcn_s_barrier();
    __builtin_amdgcn_sched_barrier(0);

    for (int t = 0; t < 50; ++t) {
        const int tn = (t < 49) ? t + 1 : 49;
        const int bsel = (t + 1) & 1;
#pragma unroll
        for (int i = 0; i < 3; ++i)
            gload_lds16(srcB[i] + (size_t)tn * 1600, &GIbuf[bsel][(i * 8 + w) * 512]);

        bf16x8 hf[7];
#pragma unroll
        for (int kk = 0; kk < 7; ++kk)
            hf[kk] = __builtin_bit_cast(bf16x8,
                *(const short8*)&hS[lo * HSTRB + kk * 32 + hi * 8]);
        f32x4 acc[5];
#pragma unroll
        for (int i = 0; i < 5; ++i) acc[i] = f32x4{0.f, 0.f, 0.f, 0.f};
#pragma unroll
        for (int i = 0; i < 5; ++i) if (i < ntl)
#pragma unroll
            for (int kk = 0; kk < 7; ++kk)
                acc[i] = __builtin_amdgcn_mfma_f32_16x16x32_bf16(hf[kk], wf[i][kk], acc[i], 0, 0, 0);

#pragma unroll
        for (int i = 0; i < 5; ++i) if (i < ntl)
#pragma unroll
            for (int r = 0; r < 4; ++r)
                gAll[gOff[i] + r * GSTR] = acc[i][r];

        asm volatile("s_waitcnt lgkmcnt(0)" ::: "memory");   // B1
        __builtin_amdgcn_s_barrier();
        __builtin_amdgcn_sched_barrier(0);
        asm volatile("s_waitcnt vmcnt(3)" ::: "memory");     // GIbuf[t&1] ready
        __builtin_amdgcn_sched_barrier(0);

        if (act) {
            const unsigned short* gib = &GIbuf[t & 1][0];
#pragma unroll
            for (int rr = 0; rr < 8; ++rr) {
                const int row = rh * 8 + rr;
                const float gi_r = bf2f(gib[row * 600 + c]);
                const float gi_z = bf2f(gib[row * 600 + 200 + c]);
                const float gi_n = bf2f(gib[row * 600 + 400 + c]);
                const float gr = gi_r + gAll[(0 * 16 + row) * GSTR + c] + bh0;
                const float gz = gi_z + gAll[(1 * 16 + row) * GSTR + c] + bh1;
                const float hn = gAll[(2 * 16 + row) * GSTR + c] + bh2;
                const float rs = __builtin_amdgcn_rcpf(1.f + __expf(-gr));
                const float zz = __builtin_amdgcn_rcpf(1.f + __expf(-gz));
                const float x  = gi_n + rs * hn;
                const float e2 = __expf(-2.f * fabsf(x));
                float th = (1.f - e2) * __builtin_amdgcn_rcpf(1.f + e2);
                th = __builtin_copysignf(th, x);
                const float h = (1.f - zz) * th + zz * h_reg[rr];
                h_reg[rr] = h;
                hS[row * HSTRB + c] = f2bf(h);
                const size_t bt = (size_t)((r0 + row) * 50 + t);
                out[bt * 350 + c] = h;                 // deter fp32
                GI[bt * 800 + c]  = f2bf(h);           // deter bf16 for k3
            }
        }

        asm volatile("s_waitcnt lgkmcnt(0)" ::: "memory");   // B2
        __builtin_amdgcn_s_barrier();
        __builtin_amdgcn_sched_barrier(0);
    }
}

// ---------------- kernel 3: heads, fully parallel over 51200 rows ----------------
__global__ __launch_bounds__(256, 1) void k3_heads(
    const unsigned short* __restrict__ GI,     // deter bf16 cols 0..199, QE cols 600..799
    const unsigned short* __restrict__ Wpq1,
    const unsigned short* __restrict__ Wpq2,
    const float* __restrict__ noise,           // [51200][30]
    const float* __restrict__ bp1,
    const float* __restrict__ bp2,
    const float* __restrict__ bq2,
    float* __restrict__ out)                   // cols 200..349
{
    __shared__ unsigned short pq[2][16 * HSTRB];
    __shared__ float ost[16 * 128];

    const int tid = threadIdx.x;
    const int w = tid >> 6, l = tid & 63;
    const int lo = l & 15, hi = l >> 4;
    const int r0 = blockIdx.x * 16;

    {   unsigned short* p0 = &pq[0][0];
        for (int i = tid; i < 2 * 16 * HSTRB; i += 256) p0[i] = 0; }
    __syncthreads();

    bf16x8 af[7];
#pragma unroll
    for (int kk = 0; kk < 7; ++kk)
        af[kk] = __builtin_bit_cast(bf16x8,
            *(const short8*)&GI[(size_t)(r0 + lo) * 800 + kk * 32 + hi * 8]);

    const int h1s = (w < 2) ? 7 * w : 14 + 6 * (w - 2);
    const int h1n = (w < 2) ? 7 : 6;
    f32x4 a2[7];
#pragma unroll
    for (int i = 0; i < 7; ++i) a2[i] = f32x4{0.f, 0.f, 0.f, 0.f};
#pragma unroll
    for (int i = 0; i < 7; ++i) if (i < h1n) {
        const int nt = h1s + i;
#pragma unroll
        for (int kk = 0; kk < 7; ++kk) {
            bf16x8 b = __builtin_bit_cast(bf16x8,
                *(const short8*)&Wpq1[((kk * 26 + nt) * 64 + l) * 8]);
            a2[i] = __builtin_amdgcn_mfma_f32_16x16x32_bf16(af[kk], b, a2[i], 0, 0, 0);
        }
    }
#pragma unroll
    for (int i = 0; i < 7; ++i) if (i < h1n) {
        const int nt = h1s + i;
        const bool isq = (nt >= 13);
        const int c1 = (isq ? (nt - 13) : nt) * 16 + lo;
        if (c1 < 200) {
#pragma unroll
            for (int r = 0; r < 4; ++r) {
                const int row = hi * 4 + r;
                float v = a2[i][r];
                if (isq) v += bf2f(GI[(size_t)(r0 + row) * 800 + 600 + c1]);  // QE (incl bq1)
                else     v += bp1[c1];
                v = (v > 0.f) ? v : expm1f(v);                                 // ELU
                pq[isq ? 1 : 0][row * HSTRB + c1] = f2bf(v);
            }
        }
    }
    __syncthreads();

    const unsigned short* srcS = &pq[(w >= 2) ? 1 : 0][0];
    bf16x8 pf[7];
#pragma unroll
    for (int kk = 0; kk < 7; ++kk)
        pf[kk] = __builtin_bit_cast(bf16x8,
            *(const short8*)&srcS[lo * HSTRB + kk * 32 + hi * 8]);
    f32x4 a3[2];
    a3[0] = f32x4{0.f, 0.f, 0.f, 0.f};
    a3[1] = f32x4{0.f, 0.f, 0.f, 0.f};
#pragma unroll
    for (int i = 0; i < 2; ++i) {
        const int nt = ((w >= 2) ? 4 : 0) + (w & 1) * 2 + i;
#pragma unroll
        for (int kk = 0; kk < 7; ++kk) {
            bf16x8 b = __builtin_bit_cast(bf16x8,
                *(const short8*)&Wpq2[((kk * 8 + nt) * 64 + l) * 8]);
            a3[i] = __builtin_amdgcn_mfma_f32_16x16x32_bf16(pf[kk], b, a3[i], 0, 0, 0);
        }
    }
#pragma unroll
    for (int i = 0; i < 2; ++i) {
        const int nt = ((w >= 2) ? 4 : 0) + (w & 1) * 2 + i;
        const int cl = (nt & 3) * 16 + lo;
        if (cl < 60) {
            const float bb = (nt < 4) ? bp2[cl] : bq2[cl];
            const int obase = ((nt < 4) ? 0 : 64) + ((cl < 30) ? cl : (32 + cl - 30));
#pragma unroll
            for (int r = 0; r < 4; ++r)
                ost[(hi * 4 + r) * 128 + obase] = a3[i][r] + bb;
        }
    }
    __syncthreads();

    for (int idx = tid; idx < 16 * 150; idx += 256) {
        const int row = idx / 150;
        const int c = 200 + (idx - row * 150);
        const size_t bt = (size_t)(r0 + row);
        const float* o = &ost[row * 128];
        float v;
        if (c < 230) {
            const int j = c - 200;
            const float qs = softplusf(o[96 + j]) + 0.1f;
            v = o[64 + j] + qs * noise[bt * 30 + j];
        }
        else if (c < 260) v = o[c - 230];
        else if (c < 290) v = softplusf(o[32 + (c - 260)]) + 0.1f;
        else if (c < 320) v = o[64 + (c - 290)];
        else              v = softplusf(o[96 + (c - 320)]) + 0.1f;
        out[bt * 350 + c] = v;
    }
}

// ---------------------------------------------------------------------------
extern "C" void kernel_launch(void* const* d_in, const int* in_sizes, int n_in,
                              void* d_out, int out_size, void* d_ws, size_t ws_size,
                              hipStream_t stream)
{
    const float* action = (const float*)d_in[0];
    const float* embed  = (const float*)d_in[1];
    const float* noise  = (const float*)d_in[2];
    const float* W_ih   = (const float*)d_in[3];
    const float* W_hh   = (const float*)d_in[4];
    const float* b_ih   = (const float*)d_in[5];
    const float* b_hh   = (const float*)d_in[6];
    const float* Wp1    = (const float*)d_in[7];
    const float* bp1    = (const float*)d_in[8];
    const float* Wp2    = (const float*)d_in[9];
    const float* bp2    = (const float*)d_in[10];
    const float* Wq1    = (const float*)d_in[11];
    const float* bq1    = (const float*)d_in[12];
    const float* Wq2    = (const float*)d_in[13];
    const float* bq2    = (const float*)d_in[14];
    (void)in_sizes; (void)n_in; (void)out_size; (void)ws_size;

    char* ws = (char*)d_ws;
    unsigned short* GI    = (unsigned short*)(ws);
    unsigned short* Bpack = (unsigned short*)(ws + OFF_BPACK);
    unsigned short* Whh_p = (unsigned short*)(ws + OFF_WHH);
    unsigned short* Wpq1  = (unsigned short*)(ws + OFF_WPQ1);
    unsigned short* Wpq2  = (unsigned short*)(ws + OFF_WPQ2);
    float* outp = (float*)d_out;

    pack_kernel<<<4222, 256, 0, stream>>>(W_ih, W_hh, Wp1, Wq1, Wp2, Wq2,
                                          Bpack, Whh_p, Wpq1, Wpq2);
    k1_gi<<<400, 512, 0, stream>>>(embed, action, W_ih, b_ih, bq1, Bpack, GI);
    k2_scan<<<64, 512, 0, stream>>>(GI, Whh_p, b_hh, outp);
    k3_heads<<<3200, 256, 0, stream>>>(GI, Wpq1, Wpq2, noise, bp1, bp2, bq2, outp);
}

// Round 12
// 423.878 us; speedup vs baseline: 1.2151x; 1.2151x over previous
//
#include <hip/hip_runtime.h>
#include <hip/hip_bf16.h>
#include <cstdint>

// ---------------------------------------------------------------------------
// WorldModel RSSM: B=1024 T=50 E=1024 A=6 S=200 H=200 L=30
// fp32 in/out; internal GEMMs bf16 MFMA w/ fp32 accum.
//
//   k1: GI[bt,0:600]=concat(a,e)@W_ih+b_ih ; GI[bt,600:800]=e@Wq1[200:]+bq1
//       tile 128x160, counted-vmcnt 2-deep pipeline. A reg-staged fp32->bf16
//       (T14 split: loads at iter top, cvt+ds_write after MFMAs) -> LDS
//       reads/wave drop 14->9 (M_rep=4 x N_rep=5, acc 80 AGPR). 36KB dbuf.
//   k2: GRU scan, 64 blocks x 8 waves, W_hh resident in regs (round 7).
//   k3: heads (fc_prior/fc_posterior + softplus + rsample) fully parallel.
// ---------------------------------------------------------------------------

typedef __attribute__((ext_vector_type(8))) short   short8;
typedef __attribute__((ext_vector_type(8))) __bf16  bf16x8;
typedef __attribute__((ext_vector_type(4))) float   f32x4;

__device__ __forceinline__ float bf2f(unsigned short u) {
    unsigned int v = ((unsigned int)u) << 16;
    return __builtin_bit_cast(float, v);
}
__device__ __forceinline__ unsigned short f2bf(float f) {
    unsigned int v = __builtin_bit_cast(unsigned int, f);
    v = v + 0x7FFFu + ((v >> 16) & 1u);   // RNE
    return (unsigned short)(v >> 16);
}
__device__ __forceinline__ float softplusf(float x) {
    return (x > 20.f) ? x : log1pf(__expf(x));
}
__device__ __forceinline__ void gload_lds16(const void* g, void* l) {
    __builtin_amdgcn_global_load_lds(
        (const __attribute__((address_space(1))) void*)g,
        (__attribute__((address_space(3))) void*)l, 16, 0, 0);
}

// ---------------- workspace layout (bytes) ----------------
#define OFF_BPACK 81920000
#define OFF_WHH   83558400
#define OFF_WPQ1  83837952
#define OFF_WPQ2  84024320

// fragment mapping (mfma_f32_16x16x32_bf16):
//   A[l&15][(l>>4)*8+j], B[(l>>4)*8+j][l&15], D[(l>>4)*4+r][l&15]
// packed B storage: elem = ((kk*NT + nt)*64 + l)*8 + j

__global__ __launch_bounds__(256) void pack_kernel(
    const float* __restrict__ W_ih, const float* __restrict__ W_hh,
    const float* __restrict__ Wp1,  const float* __restrict__ Wq1,
    const float* __restrict__ Wp2,  const float* __restrict__ Wq2,
    unsigned short* __restrict__ Bpack, unsigned short* __restrict__ Whh_p,
    unsigned short* __restrict__ Wpq1,  unsigned short* __restrict__ Wpq2)
{
    int e = blockIdx.x * 256 + threadIdx.x;
    if (e < 819200) {                       // k1: K=1024(embed), N=800
        const int j = e & 7, l = (e >> 3) & 63;
        const int nt = (e >> 9) % 50, kk = e / (512 * 50);
        const int k = kk * 32 + (l >> 4) * 8 + j;
        const int c = nt * 16 + (l & 15);
        Bpack[e] = f2bf((c < 600) ? W_ih[(6 + k) * 600 + c]
                                  : Wq1[(200 + k) * 200 + (c - 600)]);
        return;
    }
    e -= 819200;
    if (e < 139776) {                       // W_hh: K pad 224, N = 3 gates x 13 tiles
        const int j = e & 7, l = (e >> 3) & 63;
        const int nt = (e >> 9) % 39, kk = e / (512 * 39);
        const int k = kk * 32 + (l >> 4) * 8 + j;
        const int g = nt / 13, st = nt % 13;
        const int c = st * 16 + (l & 15);
        Whh_p[e] = (k < 200 && c < 200) ? f2bf(W_hh[k * 600 + g * 200 + c]) : (unsigned short)0;
        return;
    }
    e -= 139776;
    if (e < 93184) {                        // heads1: [Wp1 | Wq1[:200]] K pad 224
        const int j = e & 7, l = (e >> 3) & 63;
        const int nt = (e >> 9) % 26, kk = e / (512 * 26);
        const int k = kk * 32 + (l >> 4) * 8 + j;
        unsigned short v = 0;
        if (nt < 13) { const int c = nt * 16 + (l & 15);        if (k < 200 && c < 200) v = f2bf(Wp1[k * 200 + c]); }
        else         { const int c = (nt - 13) * 16 + (l & 15); if (k < 200 && c < 200) v = f2bf(Wq1[k * 200 + c]); }
        Wpq1[e] = v;
        return;
    }
    e -= 93184;
    if (e < 28672) {                        // heads2: [Wp2 | Wq2] N pad 64 each
        const int j = e & 7, l = (e >> 3) & 63;
        const int nt = (e >> 9) % 8, kk = e / (512 * 8);
        const int k = kk * 32 + (l >> 4) * 8 + j;
        unsigned short v = 0;
        if (nt < 4) { const int c = nt * 16 + (l & 15);       if (k < 200 && c < 60) v = f2bf(Wp2[k * 60 + c]); }
        else        { const int c = (nt - 4) * 16 + (l & 15); if (k < 200 && c < 60) v = f2bf(Wq2[k * 60 + c]); }
        Wpq2[e] = v;
    }
}

// ---------------- kernel 1: GI/QE GEMM  M=51200 N=800 K=1024 ----------------
// grid 2000 = 400 M-chunks(128 rows) x 5 N-groups(160 cols = 10 tiles).
// 256 thr = 4 waves = (mq 0..1) x (nq 0..1); wave = 4 M-subtiles x 5 N-tiles
// (acc[4][5] = 80 AGPR). Buffer (bytes): [0,10240) B 10 tiles (gload_lds);
// [10240,18432) A 8 subtiles bf16 fragment-order (reg-staged cvt).
// Per-iter: {A-loads -> fence -> B-DMA -> vmcnt(4+nB) -> bar -> MFMA ->
// vmcnt(nB) -> cvt+ds_write -> lgkm(0) -> bar}. vmcnt never drains in-loop.
#define K1_BYTES 18432
#define K1_AOFF  10240
__global__ __launch_bounds__(256, 2) void k1_gi(
    const float* __restrict__ embed,   // [51200][1024]
    const float* __restrict__ action,  // [51200][6]
    const float* __restrict__ W_ih,    // rows 0..5 = action part
    const float* __restrict__ b_ih,
    const float* __restrict__ bq1,
    const unsigned short* __restrict__ Bpack,
    unsigned short* __restrict__ GI)   // [51200][800] bf16
{
    __shared__ char bufS[2][K1_BYTES];

    const int tid = threadIdx.x;
    const int w = tid >> 6, l = tid & 63;
    const int lo = l & 15, hi = l >> 4;
    const int mq = w >> 1;                 // 0..1 -> 64-row half (4 subtiles)
    const int nq = w & 1;                  // 0..1 -> 5-tile half

    // XCD-bijective swizzle: 5 N-siblings of an M-chunk land on one XCD
    const int g    = (blockIdx.x & 7) * 250 + (blockIdx.x >> 3);
    const int mblk = g / 5;
    const int ng   = g - mblk * 5;
    const int rb   = mblk * 128;

    // ---- B stage chunks: wave w covers j = w + 4i < 10 (w<2: 3, else 2)
    const char* bsp[3]; int bdof[3];
    const int nB = (w < 2) ? 3 : 2;
#pragma unroll
    for (int i = 0; i < 3; ++i) {
        int j = w + 4 * i; if (j >= 10) j = 9;
        bsp[i]  = (const char*)Bpack + (size_t)(ng * 10 + j) * 1024 + l * 16;
        bdof[i] = j * 1024;
    }

    // ---- A reg-stage mapping: thread t handles octet (msA, lA) and (msA+4, lA)
    const int msA = tid >> 6;              // 0..3
    const int lA  = tid & 63;
    const float* aSrc1 = embed + (size_t)(rb + msA * 16 + (lA & 15)) * 1024 + (lA >> 4) * 8;
    const float* aSrc2 = aSrc1 + (size_t)64 * 1024;   // subtile msA+4 = rows +64
    const int awo1 = K1_AOFF + msA * 1024 + lA * 16;  // lane-contiguous writes
    const int awo2 = awo1 + 4096;

    f32x4 acc[4][5];
#pragma unroll
    for (int s = 0; s < 4; ++s)
#pragma unroll
        for (int i = 0; i < 5; ++i) acc[s][i] = f32x4{0.f, 0.f, 0.f, 0.f};

    // ---- prologue: A(0) regs + B(0) DMA; cvt+write buf0 A
    {
        f32x4 a1a = *(const f32x4*)(aSrc1);
        f32x4 a1b = *(const f32x4*)(aSrc1 + 4);
        f32x4 a2a = *(const f32x4*)(aSrc2);
        f32x4 a2b = *(const f32x4*)(aSrc2 + 4);
        __builtin_amdgcn_sched_barrier(0);
#pragma unroll
        for (int i = 0; i < 3; ++i) if (i < nB) {
            gload_lds16(bsp[i], &bufS[0][bdof[i]]);
            bsp[i] += 51200;
        }
        if (w < 2) asm volatile("s_waitcnt vmcnt(3)" ::: "memory");
        else       asm volatile("s_waitcnt vmcnt(2)" ::: "memory");
        __builtin_amdgcn_sched_barrier(0);
        bf16x8 t1, t2;
#pragma unroll
        for (int q = 0; q < 4; ++q) {
            t1[q] = (__bf16)a1a[q]; t1[4 + q] = (__bf16)a1b[q];
            t2[q] = (__bf16)a2a[q]; t2[4 + q] = (__bf16)a2b[q];
        }
        *(short8*)&bufS[0][awo1] = __builtin_bit_cast(short8, t1);
        *(short8*)&bufS[0][awo2] = __builtin_bit_cast(short8, t2);
    }
    asm volatile("s_waitcnt lgkmcnt(0)" ::: "memory");
    __builtin_amdgcn_s_barrier();
    __builtin_amdgcn_sched_barrier(0);

    // ---- main loop
    int cur = 0;
    for (int kk = 0; kk < 32; ++kk) {
        const int nxt = cur ^ 1;
        f32x4 a1a, a1b, a2a, a2b;
        if (kk < 31) {
            const float* p1 = aSrc1 + (size_t)(kk + 1) * 32;
            const float* p2 = aSrc2 + (size_t)(kk + 1) * 32;
            a1a = *(const f32x4*)(p1);
            a1b = *(const f32x4*)(p1 + 4);
            a2a = *(const f32x4*)(p2);
            a2b = *(const f32x4*)(p2 + 4);
            __builtin_amdgcn_sched_barrier(0);
#pragma unroll
            for (int i = 0; i < 3; ++i) if (i < nB) {
                gload_lds16(bsp[i], &bufS[nxt][bdof[i]]);
                bsp[i] += 51200;
            }
            if (w < 2) asm volatile("s_waitcnt vmcnt(7)" ::: "memory");  // drain B(kk)
            else       asm volatile("s_waitcnt vmcnt(6)" ::: "memory");
        } else {
            asm volatile("s_waitcnt vmcnt(0)" ::: "memory");
        }
        __builtin_amdgcn_s_barrier();          // buf cur fully staged
        __builtin_amdgcn_sched_barrier(0);

        // compute from cur: 4 A-frags (bf16 direct) x 5 B-tiles
        bf16x8 af[4];
#pragma unroll
        for (int s = 0; s < 4; ++s)
            af[s] = __builtin_bit_cast(bf16x8,
                *(const short8*)&bufS[cur][K1_AOFF + (mq * 4 + s) * 1024 + l * 16]);
#pragma unroll
        for (int i = 0; i < 5; ++i) {
            bf16x8 b = __builtin_bit_cast(bf16x8,
                *(const short8*)&bufS[cur][(nq * 5 + i) * 1024 + l * 16]);
#pragma unroll
            for (int s = 0; s < 4; ++s)
                acc[s][i] = __builtin_amdgcn_mfma_f32_16x16x32_bf16(af[s], b, acc[s][i], 0, 0, 0);
        }

        if (kk < 31) {
            // A(kk+1) regs landed by now (issued one MFMA-phase ago)
            if (w < 2) asm volatile("s_waitcnt vmcnt(3)" ::: "memory");  // leave B(kk+1)
            else       asm volatile("s_waitcnt vmcnt(2)" ::: "memory");
            __builtin_amdgcn_sched_barrier(0);
            bf16x8 t1, t2;
#pragma unroll
            for (int q = 0; q < 4; ++q) {
                t1[q] = (__bf16)a1a[q]; t1[4 + q] = (__bf16)a1b[q];
                t2[q] = (__bf16)a2a[q]; t2[4 + q] = (__bf16)a2b[q];
            }
            *(short8*)&bufS[nxt][awo1] = __builtin_bit_cast(short8, t1);
            *(short8*)&bufS[nxt][awo2] = __builtin_bit_cast(short8, t2);
        }

        asm volatile("s_waitcnt lgkmcnt(0)" ::: "memory");   // LDS reads+writes done
        __builtin_amdgcn_s_barrier();
        __builtin_amdgcn_sched_barrier(0);
        cur = nxt;
    }

    // ---- epilogue: bias + action(K=6) contribution, store bf16
#pragma unroll
    for (int s = 0; s < 4; ++s) {
        const int rbase = rb + (mq * 4 + s) * 16 + hi * 4;
        float av[4][6];
#pragma unroll
        for (int r = 0; r < 4; ++r)
#pragma unroll
            for (int k = 0; k < 6; ++k) av[r][k] = action[(size_t)(rbase + r) * 6 + k];
#pragma unroll
        for (int i = 0; i < 5; ++i) {
            const int col = ng * 160 + (nq * 5 + i) * 16 + lo;
            const float bias = (col < 600) ? b_ih[col] : bq1[col - 600];
            float wa[6];
            if (col < 600) {
#pragma unroll
                for (int k = 0; k < 6; ++k) wa[k] = W_ih[k * 600 + col];
            }
#pragma unroll
            for (int r = 0; r < 4; ++r) {
                float v = acc[s][i][r] + bias;
                if (col < 600) {
#pragma unroll
                    for (int k = 0; k < 6; ++k) v += av[r][k] * wa[k];
                }
                GI[(size_t)(rbase + r) * 800 + col] = f2bf(v);
            }
        }
    }
}

// ---------------- kernel 2: GRU scan, 8 waves, resident weights ----------------
#define HSTRB 232   // hS row stride in bf16 elems (K pad >=224)
#define GSTR  227   // gAll row stride in floats (odd-ish vs 32 banks)

__global__ __launch_bounds__(512, 2) void k2_scan(
    unsigned short* __restrict__ GI,           // [51200][800] bf16 (deter -> cols 0..199)
    const unsigned short* __restrict__ Whh_p,
    const float* __restrict__ b_hh,
    float* __restrict__ out)                   // [51200][350] fp32 (cols 0..199 here)
{
    __shared__ unsigned short hS[16 * HSTRB];                 // 7424 B, bf16 h
    __shared__ float gAll[3 * 16 * GSTR];                     // 43584 B
    __shared__ __align__(16) unsigned short GIbuf[2][12288];  // 49152 B

    const int tid = threadIdx.x;
    const int w = tid >> 6, l = tid & 63;
    const int lo = l & 15, hi = l >> 4;
    const int r0 = blockIdx.x * 16;

    for (int i = tid; i < 16 * HSTRB; i += 512) hS[i] = 0;

    const int t0 = w * 5;
    const int ntl = (w == 7) ? 4 : 5;
    bf16x8 wf[5][7];
#pragma unroll
    for (int i = 0; i < 5; ++i)
#pragma unroll
        for (int kk = 0; kk < 7; ++kk)
            if (i < ntl)
                wf[i][kk] = __builtin_bit_cast(bf16x8,
                    *(const short8*)&Whh_p[((kk * 39 + (t0 + i)) * 64 + l) * 8]);

    int gOff[5];
#pragma unroll
    for (int i = 0; i < 5; ++i) {
        int nt = t0 + i; if (nt > 38) nt = 38;
        const int g = nt / 13, st = nt - g * 13;
        gOff[i] = (g * 16 + hi * 4) * GSTR + st * 16 + lo;
    }

    const char* srcB[3];
#pragma unroll
    for (int i = 0; i < 3; ++i) {
        int j = (i * 8 + w) * 64 + l;
        int rj = j / 75; int cj = j - rj * 75;
        if (rj > 15) { rj = 15; cj = 74; }
        srcB[i] = (const char*)GI + (size_t)(r0 + rj) * 50 * 1600 + (size_t)cj * 16;
    }

    const int c = tid & 255;
    const int rh = tid >> 8;
    const bool act = (c < 200);
    float bh0 = 0.f, bh1 = 0.f, bh2 = 0.f;
    if (act) { bh0 = b_hh[c]; bh1 = b_hh[200 + c]; bh2 = b_hh[400 + c]; }
    float h_reg[8] = {0.f, 0.f, 0.f, 0.f, 0.f, 0.f, 0.f, 0.f};

    {
#pragma unroll
        for (int i = 0; i < 3; ++i)
            gload_lds16(srcB[i], &GIbuf[0][(i * 8 + w) * 512]);
    }
    asm volatile("s_waitcnt lgkmcnt(0)" ::: "memory");
    __builtin_amdgcn_s_barrier();
    __builtin_amdgcn_sched_barrier(0);

    for (int t = 0; t < 50; ++t) {
        const int tn = (t < 49) ? t + 1 : 49;
        const int bsel = (t + 1) & 1;
#pragma unroll
        for (int i = 0; i < 3; ++i)
            gload_lds16(srcB[i] + (size_t)tn * 1600, &GIbuf[bsel][(i * 8 + w) * 512]);

        bf16x8 hf[7];
#pragma unroll
        for (int kk = 0; kk < 7; ++kk)
            hf[kk] = __builtin_bit_cast(bf16x8,
                *(const short8*)&hS[lo * HSTRB + kk * 32 + hi * 8]);
        f32x4 acc[5];
#pragma unroll
        for (int i = 0; i < 5; ++i) acc[i] = f32x4{0.f, 0.f, 0.f, 0.f};
#pragma unroll
        for (int i = 0; i < 5; ++i) if (i < ntl)
#pragma unroll
            for (int kk = 0; kk < 7; ++kk)
                acc[i] = __builtin_amdgcn_mfma_f32_16x16x32_bf16(hf[kk], wf[i][kk], acc[i], 0, 0, 0);

#pragma unroll
        for (int i = 0; i < 5; ++i) if (i < ntl)
#pragma unroll
            for (int r = 0; r < 4; ++r)
                gAll[gOff[i] + r * GSTR] = acc[i][r];

        asm volatile("s_waitcnt lgkmcnt(0)" ::: "memory");   // B1
        __builtin_amdgcn_s_barrier();
        __builtin_amdgcn_sched_barrier(0);
        asm volatile("s_waitcnt vmcnt(3)" ::: "memory");     // GIbuf[t&1] ready
        __builtin_amdgcn_sched_barrier(0);

        if (act) {
            const unsigned short* gib = &GIbuf[t & 1][0];
#pragma unroll
            for (int rr = 0; rr < 8; ++rr) {
                const int row = rh * 8 + rr;
                const float gi_r = bf2f(gib[row * 600 + c]);
                const float gi_z = bf2f(gib[row * 600 + 200 + c]);
                const float gi_n = bf2f(gib[row * 600 + 400 + c]);
                const float gr = gi_r + gAll[(0 * 16 + row) * GSTR + c] + bh0;
                const float gz = gi_z + gAll[(1 * 16 + row) * GSTR + c] + bh1;
                const float hn = gAll[(2 * 16 + row) * GSTR + c] + bh2;
                const float rs = __builtin_amdgcn_rcpf(1.f + __expf(-gr));
                const float zz = __builtin_amdgcn_rcpf(1.f + __expf(-gz));
                const float x  = gi_n + rs * hn;
                const float e2 = __expf(-2.f * fabsf(x));
                float th = (1.f - e2) * __builtin_amdgcn_rcpf(1.f + e2);
                th = __builtin_copysignf(th, x);
                const float h = (1.f - zz) * th + zz * h_reg[rr];
                h_reg[rr] = h;
                hS[row * HSTRB + c] = f2bf(h);
                const size_t bt = (size_t)((r0 + row) * 50 + t);
                out[bt * 350 + c] = h;                 // deter fp32
                GI[bt * 800 + c]  = f2bf(h);           // deter bf16 for k3
            }
        }

        asm volatile("s_waitcnt lgkmcnt(0)" ::: "memory");   // B2
        __builtin_amdgcn_s_barrier();
        __builtin_amdgcn_sched_barrier(0);
    }
}

// ---------------- kernel 3: heads, fully parallel over 51200 rows ----------------
__global__ __launch_bounds__(256, 1) void k3_heads(
    const unsigned short* __restrict__ GI,     // deter bf16 cols 0..199, QE cols 600..799
    const unsigned short* __restrict__ Wpq1,
    const unsigned short* __restrict__ Wpq2,
    const float* __restrict__ noise,           // [51200][30]
    const float* __restrict__ bp1,
    const float* __restrict__ bp2,
    const float* __restrict__ bq2,
    float* __restrict__ out)                   // cols 200..349
{
    __shared__ unsigned short pq[2][16 * HSTRB];
    __shared__ float ost[16 * 128];

    const int tid = threadIdx.x;
    const int w = tid >> 6, l = tid & 63;
    const int lo = l & 15, hi = l >> 4;
    const int r0 = blockIdx.x * 16;

    {   unsigned short* p0 = &pq[0][0];
        for (int i = tid; i < 2 * 16 * HSTRB; i += 256) p0[i] = 0; }
    __syncthreads();

    bf16x8 af[7];
#pragma unroll
    for (int kk = 0; kk < 7; ++kk)
        af[kk] = __builtin_bit_cast(bf16x8,
            *(const short8*)&GI[(size_t)(r0 + lo) * 800 + kk * 32 + hi * 8]);

    const int h1s = (w < 2) ? 7 * w : 14 + 6 * (w - 2);
    const int h1n = (w < 2) ? 7 : 6;
    f32x4 a2[7];
#pragma unroll
    for (int i = 0; i < 7; ++i) a2[i] = f32x4{0.f, 0.f, 0.f, 0.f};
#pragma unroll
    for (int i = 0; i < 7; ++i) if (i < h1n) {
        const int nt = h1s + i;
#pragma unroll
        for (int kk = 0; kk < 7; ++kk) {
            bf16x8 b = __builtin_bit_cast(bf16x8,
                *(const short8*)&Wpq1[((kk * 26 + nt) * 64 + l) * 8]);
            a2[i] = __builtin_amdgcn_mfma_f32_16x16x32_bf16(af[kk], b, a2[i], 0, 0, 0);
        }
    }
#pragma unroll
    for (int i = 0; i < 7; ++i) if (i < h1n) {
        const int nt = h1s + i;
        const bool isq = (nt >= 13);
        const int c1 = (isq ? (nt - 13) : nt) * 16 + lo;
        if (c1 < 200) {
#pragma unroll
            for (int r = 0; r < 4; ++r) {
                const int row = hi * 4 + r;
                float v = a2[i][r];
                if (isq) v += bf2f(GI[(size_t)(r0 + row) * 800 + 600 + c1]);  // QE (incl bq1)
                else     v += bp1[c1];
                v = (v > 0.f) ? v : expm1f(v);                                 // ELU
                pq[isq ? 1 : 0][row * HSTRB + c1] = f2bf(v);
            }
        }
    }
    __syncthreads();

    const unsigned short* srcS = &pq[(w >= 2) ? 1 : 0][0];
    bf16x8 pf[7];
#pragma unroll
    for (int kk = 0; kk < 7; ++kk)
        pf[kk] = __builtin_bit_cast(bf16x8,
            *(const short8*)&srcS[lo * HSTRB + kk * 32 + hi * 8]);
    f32x4 a3[2];
    a3[0] = f32x4{0.f, 0.f, 0.f, 0.f};
    a3[1] = f32x4{0.f, 0.f, 0.f, 0.f};
#pragma unroll
    for (int i = 0; i < 2; ++i) {
        const int nt = ((w >= 2) ? 4 : 0) + (w & 1) * 2 + i;
#pragma unroll
        for (int kk = 0; kk < 7; ++kk) {
            bf16x8 b = __builtin_bit_cast(bf16x8,
                *(const short8*)&Wpq2[((kk * 8 + nt) * 64 + l) * 8]);
            a3[i] = __builtin_amdgcn_mfma_f32_16x16x32_bf16(pf[kk], b, a3[i], 0, 0, 0);
        }
    }
#pragma unroll
    for (int i = 0; i < 2; ++i) {
        const int nt = ((w >= 2) ? 4 : 0) + (w & 1) * 2 + i;
        const int cl = (nt & 3) * 16 + lo;
        if (cl < 60) {
            const float bb = (nt < 4) ? bp2[cl] : bq2[cl];
            const int obase = ((nt < 4) ? 0 : 64) + ((cl < 30) ? cl : (32 + cl - 30));
#pragma unroll
            for (int r = 0; r < 4; ++r)
                ost[(hi * 4 + r) * 128 + obase] = a3[i][r] + bb;
        }
    }
    __syncthreads();

    for (int idx = tid; idx < 16 * 150; idx += 256) {
        const int row = idx / 150;
        const int c = 200 + (idx - row * 150);
        const size_t bt = (size_t)(r0 + row);
        const float* o = &ost[row * 128];
        float v;
        if (c < 230) {
            const int j = c - 200;
            const float qs = softplusf(o[96 + j]) + 0.1f;
            v = o[64 + j] + qs * noise[bt * 30 + j];
        }
        else if (c < 260) v = o[c - 230];
        else if (c < 290) v = softplusf(o[32 + (c - 260)]) + 0.1f;
        else if (c < 320) v = o[64 + (c - 290)];
        else              v = softplusf(o[96 + (c - 320)]) + 0.1f;
        out[bt * 350 + c] = v;
    }
}

// ---------------------------------------------------------------------------
extern "C" void kernel_launch(void* const* d_in, const int* in_sizes, int n_in,
                              void* d_out, int out_size, void* d_ws, size_t ws_size,
                              hipStream_t stream)
{
    const float* action = (const float*)d_in[0];
    const float* embed  = (const float*)d_in[1];
    const float* noise  = (const float*)d_in[2];
    const float* W_ih   = (const float*)d_in[3];
    const float* W_hh   = (const float*)d_in[4];
    const float* b_ih   = (const float*)d_in[5];
    const float* b_hh   = (const float*)d_in[6];
    const float* Wp1    = (const float*)d_in[7];
    const float* bp1    = (const float*)d_in[8];
    const float* Wp2    = (const float*)d_in[9];
    const float* bp2    = (const float*)d_in[10];
    const float* Wq1    = (const float*)d_in[11];
    const float* bq1    = (const float*)d_in[12];
    const float* Wq2    = (const float*)d_in[13];
    const float* bq2    = (const float*)d_in[14];
    (void)in_sizes; (void)n_in; (void)out_size; (void)ws_size;

    char* ws = (char*)d_ws;
    unsigned short* GI    = (unsigned short*)(ws);
    unsigned short* Bpack = (unsigned short*)(ws + OFF_BPACK);
    unsigned short* Whh_p = (unsigned short*)(ws + OFF_WHH);
    unsigned short* Wpq1  = (unsigned short*)(ws + OFF_WPQ1);
    unsigned short* Wpq2  = (unsigned short*)(ws + OFF_WPQ2);
    float* outp = (float*)d_out;

    pack_kernel<<<4222, 256, 0, stream>>>(W_ih, W_hh, Wp1, Wq1, Wp2, Wq2,
                                          Bpack, Whh_p, Wpq1, Wpq2);
    k1_gi<<<2000, 256, 0, stream>>>(embed, action, W_ih, b_ih, bq1, Bpack, GI);
    k2_scan<<<64, 512, 0, stream>>>(GI, Whh_p, b_hh, outp);
    k3_heads<<<3200, 256, 0, stream>>>(GI, Wpq1, Wpq2, noise, bp1, bp2, bq2, outp);
}